// Round 13
// baseline (98.225 us; speedup 1.0000x reference)
//
#include <hip/hip_runtime.h>

#define HP 192
#define WP 192
#define NPIX (HP * WP)   // 36864
#define SG 24
#define KSTRU 72         // smK/smV row stride in ushorts (f16): 144 B
#define PSTR 12          // smpi row stride (floats)
#define PRE16 33         // preLds16 row stride in uints (f16 pairs)

typedef _Float16 h2 __attribute__((ext_vector_type(2)));

__device__ __forceinline__ unsigned int h2pack(float a, float b) {
  h2 r;
  r[0] = (_Float16)a;
  r[1] = (_Float16)b;
  return __builtin_bit_cast(unsigned int, r);
}
__device__ __forceinline__ h2 ash2(unsigned int u) {
  return __builtin_bit_cast(h2, u);
}

// ---------------- Kernel 1: QKV projection -----------------------------------
// grid (144, 6): jb picks 32 output cols of [q|k|v]. ALL outputs packed f16
// (q pre-scaled by hd^-0.5*log2(e) for exp2 in attn). Write traffic 14 MB.
__global__ __launch_bounds__(256) void qkv_kernel(
    const float* __restrict__ x,
    const float* __restrict__ w_qk,
    const float* __restrict__ w_v,
    unsigned int* __restrict__ qb16, unsigned int* __restrict__ kb16,
    unsigned int* __restrict__ vb16) {
  const int jb = blockIdx.y;  // 0..5
  const int pix = blockIdx.x * 256 + threadIdx.x;
  float xv[64];
#pragma unroll
  for (int c = 0; c < 64; ++c) xv[c] = x[c * NPIX + pix];
  float acc[32];
#pragma unroll
  for (int j = 0; j < 32; ++j) acc[j] = 0.f;
  const int j0 = jb * 32;
  if (jb < 4) {
#pragma unroll
    for (int c = 0; c < 64; ++c) {
      const float* wr = w_qk + c * 128 + j0;
      const float xc = xv[c];
#pragma unroll
      for (int j = 0; j < 32; ++j) acc[j] = fmaf(xc, wr[j], acc[j]);
    }
  } else {
#pragma unroll
    for (int c = 0; c < 64; ++c) {
      const float* wr = w_v + c * 64 + (j0 - 128);
      const float xc = xv[c];
#pragma unroll
      for (int j = 0; j < 32; ++j) acc[j] = fmaf(xc, wr[j], acc[j]);
    }
  }
  unsigned int* dst;
  float mul = 1.0f;
  if (jb < 2) {
    dst = qb16 + (size_t)pix * 32 + j0 / 2;
    mul = 0.25f * 1.44269504089f;  // hd^-0.5 * log2(e)
  } else if (jb < 4) {
    dst = kb16 + (size_t)pix * 32 + (j0 - 64) / 2;
  } else {
    dst = vb16 + (size_t)pix * 32 + (j0 - 128) / 2;
  }
#pragma unroll
  for (int j = 0; j < 16; ++j)
    dst[j] = h2pack(acc[2 * j] * mul, acc[2 * j + 1] * mul);
}

// ---------------- Kernel 2: attention + fused output projection --------------
// Block = 512 threads = 64 px x 4 heads x 2 splits. K AND V staged in LDS as
// f16 (straight uint4 copies; 72.6 KB total -> 2 blocks/CU). Pass 1 computes
// e = exp2(q.k) per neighbor and KEEPS e[25] in registers (full unroll ->
// compile-time indices -> no scratch); pass 2 only does pi-dot + V-accumulate
// (v_fma_mix from f16). __launch_bounds__(512,4) caps VGPR at 128.
__global__ __launch_bounds__(512, 4) void attn_kernel(
    const unsigned int* __restrict__ qb16, const unsigned int* __restrict__ kb16,
    const unsigned int* __restrict__ vb16, const float* __restrict__ sims,
    const float* __restrict__ w_proj, float* __restrict__ out) {
  __shared__ __align__(16) unsigned short smK[196 * KSTRU];
  __shared__ __align__(16) unsigned short smV[196 * KSTRU];
  __shared__ __align__(16) float smpi[196 * PSTR];
  __shared__ __align__(16) unsigned int preLds16[64 * PRE16];
  const int tile = blockIdx.x;
  const int th = tile / 24, tw = tile % 24;
  const int rowBase = th * 8 - 3, colBase = tw * 8 - 3;
  const int tid = threadIdx.x;

  // ---- stage K and V tiles: straight uint4 copies (already f16-packed) ----
  for (int i = tid; i < 196 * 8; i += 512) {
    const int loc = i >> 3, c4 = i & 7;
    const int rl = loc / 14, cl = loc - rl * 14;
    const int r = rowBase + rl, c = colBase + cl;
    uint4 k4 = make_uint4(0u, 0u, 0u, 0u);
    uint4 v4 = make_uint4(0u, 0u, 0u, 0u);
    if (r >= 0 && r < HP && c >= 0 && c < WP) {
      const size_t base = (size_t)(r * WP + c) * 32 + (c4 << 2);
      k4 = *(const uint4*)(kb16 + base);
      v4 = *(const uint4*)(vb16 + base);
    }
    *(uint4*)(smK + loc * KSTRU + (c4 << 3)) = k4;
    *(uint4*)(smV + loc * KSTRU + (c4 << 3)) = v4;
  }
  // ---- stage pi table ----
  for (int i = tid; i < 196 * 9; i += 512) {
    const int loc = i / 9, s = i - loc * 9;
    const int rl = loc / 14, cl = loc - rl * 14;
    const int r = rowBase + rl, c = colBase + cl;
    const int dh = s / 3, dw = s - dh * 3;
    const int shi = th + dh - 1, swj = tw + dw - 1;
    float val = 0.f;
    if (shi >= 0 && shi < SG && swj >= 0 && swj < SG && r >= 0 && r < HP &&
        c >= 0 && c < WP)
      val = sims[((size_t)(r * WP + c)) * (SG * SG) + shi * SG + swj];
    smpi[loc * PSTR + s] = val;
  }
  __syncthreads();

  const int split = tid & 1;
  const int head = (tid >> 1) & 3;
  const int pl = tid >> 3;  // pixel-in-tile 0..63
  const int py = pl >> 3, px = pl & 7;
  const int h = th * 8 + py, w = tw * 8 + px;
  const int pix = h * WP + w;
  int hs = h - 3;
  hs = hs < 0 ? 0 : (hs > HP - 7 ? HP - 7 : hs);
  int wsb = w - 3;
  wsb = wsb < 0 ? 0 : (wsb > WP - 7 ? WP - 7 : wsb);
  const int rl0 = hs - rowBase;   // 0..7
  const int cl0 = wsb - colBase;  // 0..7
  const int hq = head << 4;       // head channel base in halves
  const int hu = head << 3;       // head base in uints

  // q: straight f16 load (pre-scaled by qkv)
  const uint4 qa = *(const uint4*)(qb16 + (size_t)pix * 32 + hu);
  const uint4 qc = *(const uint4*)(qb16 + (size_t)pix * 32 + hu + 4);
  const h2 qh0 = ash2(qa.x), qh1 = ash2(qa.y), qh2 = ash2(qa.z),
           qh3 = ash2(qa.w);
  const h2 qh4 = ash2(qc.x), qh5 = ash2(qc.y), qh6 = ash2(qc.z),
           qh7 = ash2(qc.w);

#define DOT8(t, kp)                                           \
  {                                                           \
    const uint4 ka = *(const uint4*)(kp);                     \
    const uint4 kc = *(const uint4*)((kp) + 8);               \
    float t0 = 0.f, t1 = 0.f;                                 \
    t0 = __builtin_amdgcn_fdot2(ash2(ka.x), qh0, t0, false);  \
    t0 = __builtin_amdgcn_fdot2(ash2(ka.y), qh1, t0, false);  \
    t0 = __builtin_amdgcn_fdot2(ash2(ka.z), qh2, t0, false);  \
    t0 = __builtin_amdgcn_fdot2(ash2(ka.w), qh3, t0, false);  \
    t1 = __builtin_amdgcn_fdot2(ash2(kc.x), qh4, t1, false);  \
    t1 = __builtin_amdgcn_fdot2(ash2(kc.y), qh5, t1, false);  \
    t1 = __builtin_amdgcn_fdot2(ash2(kc.z), qh6, t1, false);  \
    t1 = __builtin_amdgcn_fdot2(ash2(kc.w), qh7, t1, false);  \
    t = t0 + t1;                                              \
  }

  // ---- pass 1 (FULL unroll): e[i] kept in registers; partial S, D9 ----
  float e[25];
  float D9[9];
#pragma unroll
  for (int s = 0; s < 9; ++s) D9[s] = 0.f;
  float S = 0.f;
#pragma unroll
  for (int i = 0; i < 25; ++i) {
    const int n = (i << 1) | split;
    if (n < 49) {
      const int kh = (n * 37) >> 8;   // exact n/7 for n<49
      const int kw = n - kh * 7;
      const int loc = (rl0 + kh) * 14 + cl0 + kw;
      float t;
      DOT8(t, smK + loc * KSTRU + hq)
      const float ev = exp2f(t);
      e[i] = ev;
      S += ev;
      const float* pp = smpi + loc * PSTR;
      const float4 p0 = *(const float4*)pp;
      const float4 p1 = *(const float4*)(pp + 4);
      const float p8 = pp[8];
      D9[0] = fmaf(ev, p0.x, D9[0]);
      D9[1] = fmaf(ev, p0.y, D9[1]);
      D9[2] = fmaf(ev, p0.z, D9[2]);
      D9[3] = fmaf(ev, p0.w, D9[3]);
      D9[4] = fmaf(ev, p1.x, D9[4]);
      D9[5] = fmaf(ev, p1.y, D9[5]);
      D9[6] = fmaf(ev, p1.z, D9[6]);
      D9[7] = fmaf(ev, p1.w, D9[7]);
      D9[8] = fmaf(ev, p8, D9[8]);
    } else {
      e[i] = 0.f;
    }
  }
#undef DOT8
  S += __shfl_xor(S, 1);
#pragma unroll
  for (int s = 0; s < 9; ++s) D9[s] += __shfl_xor(D9[s], 1);

  // ---- coef_s = ws[s] / (D[s] + 1e-10*S) ----
  float coef[9];
  {
    const float* pp = smpi + ((h - rowBase) * 14 + (w - colBase)) * PSTR;
    const float4 p0 = *(const float4*)pp;
    const float4 p1 = *(const float4*)(pp + 4);
    const float p8 = pp[8];
    const float epsS = 1e-10f * S;
    coef[0] = p0.x / (D9[0] + epsS);
    coef[1] = p0.y / (D9[1] + epsS);
    coef[2] = p0.z / (D9[2] + epsS);
    coef[3] = p0.w / (D9[3] + epsS);
    coef[4] = p1.x / (D9[4] + epsS);
    coef[5] = p1.y / (D9[5] + epsS);
    coef[6] = p1.z / (D9[6] + epsS);
    coef[7] = p1.w / (D9[7] + epsS);
    coef[8] = p8 / (D9[8] + epsS);
  }

  // ---- pass 2 (FULL unroll): a2 = e[i]*(coef.pi); o += a2 * V(LDS f16) ----
  float4 o0 = make_float4(0.f, 0.f, 0.f, 0.f);
  float4 o1 = make_float4(0.f, 0.f, 0.f, 0.f);
  float4 o2 = make_float4(0.f, 0.f, 0.f, 0.f);
  float4 o3 = make_float4(0.f, 0.f, 0.f, 0.f);
#pragma unroll
  for (int i = 0; i < 25; ++i) {
    const int n = (i << 1) | split;
    if (n < 49) {
      const int kh = (n * 37) >> 8;
      const int kw = n - kh * 7;
      const int loc = (rl0 + kh) * 14 + cl0 + kw;
      const float* pp = smpi + loc * PSTR;
      const float4 p0 = *(const float4*)pp;
      const float4 p1 = *(const float4*)(pp + 4);
      const float p8 = pp[8];
      const float tca = coef[0] * p0.x + coef[1] * p0.y;
      const float tcb = coef[2] * p0.z + coef[3] * p0.w;
      const float tcc = coef[4] * p1.x + coef[5] * p1.y;
      const float tcd = coef[6] * p1.z + coef[7] * p1.w;
      const float tc = ((tca + tcb) + (tcc + tcd)) + coef[8] * p8;
      const float a2 = e[i] * tc;
      const unsigned short* vp = smV + loc * KSTRU + hq;
      const uint4 va = *(const uint4*)vp;
      const uint4 vc = *(const uint4*)(vp + 8);
      const h2 v0 = ash2(va.x), v1 = ash2(va.y), v2 = ash2(va.z),
               v3 = ash2(va.w);
      const h2 v4 = ash2(vc.x), v5 = ash2(vc.y), v6 = ash2(vc.z),
               v7 = ash2(vc.w);
      o0.x = fmaf(a2, (float)v0[0], o0.x);
      o0.y = fmaf(a2, (float)v0[1], o0.y);
      o0.z = fmaf(a2, (float)v1[0], o0.z);
      o0.w = fmaf(a2, (float)v1[1], o0.w);
      o1.x = fmaf(a2, (float)v2[0], o1.x);
      o1.y = fmaf(a2, (float)v2[1], o1.y);
      o1.z = fmaf(a2, (float)v3[0], o1.z);
      o1.w = fmaf(a2, (float)v3[1], o1.w);
      o2.x = fmaf(a2, (float)v4[0], o2.x);
      o2.y = fmaf(a2, (float)v4[1], o2.y);
      o2.z = fmaf(a2, (float)v5[0], o2.z);
      o2.w = fmaf(a2, (float)v5[1], o2.w);
      o3.x = fmaf(a2, (float)v6[0], o3.x);
      o3.y = fmaf(a2, (float)v6[1], o3.y);
      o3.z = fmaf(a2, (float)v7[0], o3.z);
      o3.w = fmaf(a2, (float)v7[1], o3.w);
    }
  }

  // ---- combine lane pair; write packed f16 pairs to preLds16 ----
  o0.x += __shfl_xor(o0.x, 1); o0.y += __shfl_xor(o0.y, 1);
  o0.z += __shfl_xor(o0.z, 1); o0.w += __shfl_xor(o0.w, 1);
  o1.x += __shfl_xor(o1.x, 1); o1.y += __shfl_xor(o1.y, 1);
  o1.z += __shfl_xor(o1.z, 1); o1.w += __shfl_xor(o1.w, 1);
  o2.x += __shfl_xor(o2.x, 1); o2.y += __shfl_xor(o2.y, 1);
  o2.z += __shfl_xor(o2.z, 1); o2.w += __shfl_xor(o2.w, 1);
  o3.x += __shfl_xor(o3.x, 1); o3.y += __shfl_xor(o3.y, 1);
  o3.z += __shfl_xor(o3.z, 1); o3.w += __shfl_xor(o3.w, 1);
  {
    unsigned int* pw = preLds16 + pl * PRE16 + (hq >> 1) + split * 4;
    const float4 lo = split ? o2 : o0;
    const float4 hi = split ? o3 : o1;
    pw[0] = h2pack(lo.x, lo.y);
    pw[1] = h2pack(lo.z, lo.w);
    pw[2] = h2pack(hi.x, hi.y);
    pw[3] = h2pack(hi.z, hi.w);
  }
  __syncthreads();

  // ---- fused output projection: 8 groups x 8 cols, w_proj scalar ----------
  const int jb2 = __builtin_amdgcn_readfirstlane(tid >> 6);  // wave-uniform
  const int px2 = tid & 63;
  const int j0 = jb2 * 8;
  const int opix = (th * 8 + (px2 >> 3)) * WP + tw * 8 + (px2 & 7);
  float acc[8];
#pragma unroll
  for (int j = 0; j < 8; ++j) acc[j] = 0.f;
  const unsigned int* prow = preLds16 + px2 * PRE16;
#pragma unroll 8
  for (int cp = 0; cp < 32; ++cp) {
    const h2 hh = ash2(prow[cp]);
    const float xc0 = (float)hh[0];
    const float xc1 = (float)hh[1];
    const float* w0 = w_proj + (2 * cp) * 64 + j0;      // scalar rows
    const float* w1 = w_proj + (2 * cp + 1) * 64 + j0;
#pragma unroll
    for (int j = 0; j < 8; ++j)
      acc[j] = fmaf(xc1, w1[j], fmaf(xc0, w0[j], acc[j]));
  }
#pragma unroll
  for (int j = 0; j < 8; ++j) out[(size_t)(j0 + j) * NPIX + opix] = acc[j];
}

extern "C" void kernel_launch(void* const* d_in, const int* in_sizes, int n_in,
                              void* d_out, int out_size, void* d_ws,
                              size_t ws_size, hipStream_t stream) {
  const float* x = (const float*)d_in[0];
  const float* sims = (const float*)d_in[1];
  const float* w_qk = (const float*)d_in[2];
  const float* w_v = (const float*)d_in[3];
  const float* w_proj = (const float*)d_in[4];
  float* out = (float*)d_out;

  unsigned int* qb16 = (unsigned int*)d_ws;
  unsigned int* kb16 = qb16 + (size_t)NPIX * 32;
  unsigned int* vb16 = kb16 + (size_t)NPIX * 32;

  qkv_kernel<<<dim3(144, 6), 256, 0, stream>>>(x, w_qk, w_v, qb16, kb16, vb16);
  attn_kernel<<<dim3(576), 512, 0, stream>>>(qb16, kb16, vb16, sims, w_proj,
                                             out);
}

// Round 14
// 81.365 us; speedup vs baseline: 1.2072x; 1.2072x over previous
//
#include <hip/hip_runtime.h>

#define HP 192
#define WP 192
#define NPIX (HP * WP)   // 36864
#define SG 24
#define KSTRU 72         // smK/smV row stride in ushorts (f16): 144 B
#define PSTR 12          // smpi row stride (floats)
#define PRE16 33         // preLds16 row stride in uints (f16 pairs)

typedef _Float16 h2 __attribute__((ext_vector_type(2)));

__device__ __forceinline__ unsigned int h2pack(float a, float b) {
  h2 r;
  r[0] = (_Float16)a;
  r[1] = (_Float16)b;
  return __builtin_bit_cast(unsigned int, r);
}
__device__ __forceinline__ h2 ash2(unsigned int u) {
  return __builtin_bit_cast(h2, u);
}

// ---------------- Kernel 1: QKV projection (r13, all-f16 outputs) -------------
__global__ __launch_bounds__(256) void qkv_kernel(
    const float* __restrict__ x,
    const float* __restrict__ w_qk,
    const float* __restrict__ w_v,
    unsigned int* __restrict__ qb16, unsigned int* __restrict__ kb16,
    unsigned int* __restrict__ vb16) {
  const int jb = blockIdx.y;  // 0..5
  const int pix = blockIdx.x * 256 + threadIdx.x;
  float xv[64];
#pragma unroll
  for (int c = 0; c < 64; ++c) xv[c] = x[c * NPIX + pix];
  float acc[32];
#pragma unroll
  for (int j = 0; j < 32; ++j) acc[j] = 0.f;
  const int j0 = jb * 32;
  if (jb < 4) {
#pragma unroll
    for (int c = 0; c < 64; ++c) {
      const float* wr = w_qk + c * 128 + j0;
      const float xc = xv[c];
#pragma unroll
      for (int j = 0; j < 32; ++j) acc[j] = fmaf(xc, wr[j], acc[j]);
    }
  } else {
#pragma unroll
    for (int c = 0; c < 64; ++c) {
      const float* wr = w_v + c * 64 + (j0 - 128);
      const float xc = xv[c];
#pragma unroll
      for (int j = 0; j < 32; ++j) acc[j] = fmaf(xc, wr[j], acc[j]);
    }
  }
  unsigned int* dst;
  float mul = 1.0f;
  if (jb < 2) {
    dst = qb16 + (size_t)pix * 32 + j0 / 2;
    mul = 0.25f * 1.44269504089f;  // hd^-0.5 * log2(e)
  } else if (jb < 4) {
    dst = kb16 + (size_t)pix * 32 + (j0 - 64) / 2;
  } else {
    dst = vb16 + (size_t)pix * 32 + (j0 - 128) / 2;
  }
#pragma unroll
  for (int j = 0; j < 16; ++j)
    dst[j] = h2pack(acc[2 * j] * mul, acc[2 * j + 1] * mul);
}

// ---------------- Kernel 2: attention + fused output projection --------------
// Block = 512 threads = 64 px x 4 heads x 2 splits (r12 structure: NO e[]
// array, pass 2 recomputes DOT8+exp2 -> zero spill by construction).
// K AND V staged in LDS f16 (straight uint4 copies, 72.6 KB -> 2 blocks/CU):
// no global gathers left in the hot loops. Plain launch bounds (no min-waves
// hint -- r10/r13 showed it forces VGPR down and spills).
__global__ __launch_bounds__(512) void attn_kernel(
    const unsigned int* __restrict__ qb16, const unsigned int* __restrict__ kb16,
    const unsigned int* __restrict__ vb16, const float* __restrict__ sims,
    const float* __restrict__ w_proj, float* __restrict__ out) {
  __shared__ __align__(16) unsigned short smK[196 * KSTRU];
  __shared__ __align__(16) unsigned short smV[196 * KSTRU];
  __shared__ __align__(16) float smpi[196 * PSTR];
  __shared__ __align__(16) unsigned int preLds16[64 * PRE16];
  const int tile = blockIdx.x;
  const int th = tile / 24, tw = tile % 24;
  const int rowBase = th * 8 - 3, colBase = tw * 8 - 3;
  const int tid = threadIdx.x;

  // ---- stage K and V tiles: straight uint4 copies (already f16-packed) ----
  for (int i = tid; i < 196 * 8; i += 512) {
    const int loc = i >> 3, c4 = i & 7;
    const int rl = loc / 14, cl = loc - rl * 14;
    const int r = rowBase + rl, c = colBase + cl;
    uint4 k4 = make_uint4(0u, 0u, 0u, 0u);
    uint4 v4 = make_uint4(0u, 0u, 0u, 0u);
    if (r >= 0 && r < HP && c >= 0 && c < WP) {
      const size_t base = (size_t)(r * WP + c) * 32 + (c4 << 2);
      k4 = *(const uint4*)(kb16 + base);
      v4 = *(const uint4*)(vb16 + base);
    }
    *(uint4*)(smK + loc * KSTRU + (c4 << 3)) = k4;
    *(uint4*)(smV + loc * KSTRU + (c4 << 3)) = v4;
  }
  // ---- stage pi table ----
  for (int i = tid; i < 196 * 9; i += 512) {
    const int loc = i / 9, s = i - loc * 9;
    const int rl = loc / 14, cl = loc - rl * 14;
    const int r = rowBase + rl, c = colBase + cl;
    const int dh = s / 3, dw = s - dh * 3;
    const int shi = th + dh - 1, swj = tw + dw - 1;
    float val = 0.f;
    if (shi >= 0 && shi < SG && swj >= 0 && swj < SG && r >= 0 && r < HP &&
        c >= 0 && c < WP)
      val = sims[((size_t)(r * WP + c)) * (SG * SG) + shi * SG + swj];
    smpi[loc * PSTR + s] = val;
  }
  __syncthreads();

  const int split = tid & 1;
  const int head = (tid >> 1) & 3;
  const int pl = tid >> 3;  // pixel-in-tile 0..63
  const int py = pl >> 3, px = pl & 7;
  const int h = th * 8 + py, w = tw * 8 + px;
  const int pix = h * WP + w;
  int hs = h - 3;
  hs = hs < 0 ? 0 : (hs > HP - 7 ? HP - 7 : hs);
  int wsb = w - 3;
  wsb = wsb < 0 ? 0 : (wsb > WP - 7 ? WP - 7 : wsb);
  const int rl0 = hs - rowBase;   // 0..7
  const int cl0 = wsb - colBase;  // 0..7
  const int hq = head << 4;       // head channel base in halves
  const int hu = head << 3;       // head base in uints

  // q: straight f16 load (pre-scaled by qkv)
  const uint4 qa = *(const uint4*)(qb16 + (size_t)pix * 32 + hu);
  const uint4 qc = *(const uint4*)(qb16 + (size_t)pix * 32 + hu + 4);
  const h2 qh0 = ash2(qa.x), qh1 = ash2(qa.y), qh2 = ash2(qa.z),
           qh3 = ash2(qa.w);
  const h2 qh4 = ash2(qc.x), qh5 = ash2(qc.y), qh6 = ash2(qc.z),
           qh7 = ash2(qc.w);

#define DOT8(t, kp)                                           \
  {                                                           \
    const uint4 ka = *(const uint4*)(kp);                     \
    const uint4 kc = *(const uint4*)((kp) + 8);               \
    float t0 = 0.f, t1 = 0.f;                                 \
    t0 = __builtin_amdgcn_fdot2(ash2(ka.x), qh0, t0, false);  \
    t0 = __builtin_amdgcn_fdot2(ash2(ka.y), qh1, t0, false);  \
    t0 = __builtin_amdgcn_fdot2(ash2(ka.z), qh2, t0, false);  \
    t0 = __builtin_amdgcn_fdot2(ash2(ka.w), qh3, t0, false);  \
    t1 = __builtin_amdgcn_fdot2(ash2(kc.x), qh4, t1, false);  \
    t1 = __builtin_amdgcn_fdot2(ash2(kc.y), qh5, t1, false);  \
    t1 = __builtin_amdgcn_fdot2(ash2(kc.z), qh6, t1, false);  \
    t1 = __builtin_amdgcn_fdot2(ash2(kc.w), qh7, t1, false);  \
    t = t0 + t1;                                              \
  }

  // ---- pass 1: ~25 neighbors -> partial S, D9 (no per-neighbor storage) ----
  float D9[9];
#pragma unroll
  for (int s = 0; s < 9; ++s) D9[s] = 0.f;
  float S = 0.f;
#pragma unroll 5
  for (int i = 0; i < 25; ++i) {
    const int n = (i << 1) | split;
    if (n < 49) {
      const int kh = (n * 37) >> 8;   // exact n/7 for n<49
      const int kw = n - kh * 7;
      const int loc = (rl0 + kh) * 14 + cl0 + kw;
      float t;
      DOT8(t, smK + loc * KSTRU + hq)
      const float e = exp2f(t);
      S += e;
      const float* pp = smpi + loc * PSTR;
      const float4 p0 = *(const float4*)pp;
      const float4 p1 = *(const float4*)(pp + 4);
      const float p8 = pp[8];
      D9[0] = fmaf(e, p0.x, D9[0]);
      D9[1] = fmaf(e, p0.y, D9[1]);
      D9[2] = fmaf(e, p0.z, D9[2]);
      D9[3] = fmaf(e, p0.w, D9[3]);
      D9[4] = fmaf(e, p1.x, D9[4]);
      D9[5] = fmaf(e, p1.y, D9[5]);
      D9[6] = fmaf(e, p1.z, D9[6]);
      D9[7] = fmaf(e, p1.w, D9[7]);
      D9[8] = fmaf(e, p8, D9[8]);
    }
  }
  S += __shfl_xor(S, 1);
#pragma unroll
  for (int s = 0; s < 9; ++s) D9[s] += __shfl_xor(D9[s], 1);

  // ---- coef_s = ws[s] / (D[s] + 1e-10*S) ----
  float coef[9];
  {
    const float* pp = smpi + ((h - rowBase) * 14 + (w - colBase)) * PSTR;
    const float4 p0 = *(const float4*)pp;
    const float4 p1 = *(const float4*)(pp + 4);
    const float p8 = pp[8];
    const float epsS = 1e-10f * S;
    coef[0] = p0.x / (D9[0] + epsS);
    coef[1] = p0.y / (D9[1] + epsS);
    coef[2] = p0.z / (D9[2] + epsS);
    coef[3] = p0.w / (D9[3] + epsS);
    coef[4] = p1.x / (D9[4] + epsS);
    coef[5] = p1.y / (D9[5] + epsS);
    coef[6] = p1.z / (D9[6] + epsS);
    coef[7] = p1.w / (D9[7] + epsS);
    coef[8] = p8 / (D9[8] + epsS);
  }

  // ---- pass 2: recompute t,e; a2 = e*(coef.pi); o += a2 * V(LDS f16) ----
  float4 o0 = make_float4(0.f, 0.f, 0.f, 0.f);
  float4 o1 = make_float4(0.f, 0.f, 0.f, 0.f);
  float4 o2 = make_float4(0.f, 0.f, 0.f, 0.f);
  float4 o3 = make_float4(0.f, 0.f, 0.f, 0.f);
#pragma unroll 5
  for (int i = 0; i < 25; ++i) {
    const int n = (i << 1) | split;
    if (n < 49) {
      const int kh = (n * 37) >> 8;
      const int kw = n - kh * 7;
      const int loc = (rl0 + kh) * 14 + cl0 + kw;
      float t;
      DOT8(t, smK + loc * KSTRU + hq)
      const float e = exp2f(t);
      const float* pp = smpi + loc * PSTR;
      const float4 p0 = *(const float4*)pp;
      const float4 p1 = *(const float4*)(pp + 4);
      const float p8 = pp[8];
      const float tca = coef[0] * p0.x + coef[1] * p0.y;
      const float tcb = coef[2] * p0.z + coef[3] * p0.w;
      const float tcc = coef[4] * p1.x + coef[5] * p1.y;
      const float tcd = coef[6] * p1.z + coef[7] * p1.w;
      const float tc = ((tca + tcb) + (tcc + tcd)) + coef[8] * p8;
      const float a2 = e * tc;
      const unsigned short* vp = smV + loc * KSTRU + hq;
      const uint4 va = *(const uint4*)vp;
      const uint4 vc = *(const uint4*)(vp + 8);
      const h2 v0 = ash2(va.x), v1 = ash2(va.y), v2 = ash2(va.z),
               v3 = ash2(va.w);
      const h2 v4 = ash2(vc.x), v5 = ash2(vc.y), v6 = ash2(vc.z),
               v7 = ash2(vc.w);
      o0.x = fmaf(a2, (float)v0[0], o0.x);
      o0.y = fmaf(a2, (float)v0[1], o0.y);
      o0.z = fmaf(a2, (float)v1[0], o0.z);
      o0.w = fmaf(a2, (float)v1[1], o0.w);
      o1.x = fmaf(a2, (float)v2[0], o1.x);
      o1.y = fmaf(a2, (float)v2[1], o1.y);
      o1.z = fmaf(a2, (float)v3[0], o1.z);
      o1.w = fmaf(a2, (float)v3[1], o1.w);
      o2.x = fmaf(a2, (float)v4[0], o2.x);
      o2.y = fmaf(a2, (float)v4[1], o2.y);
      o2.z = fmaf(a2, (float)v5[0], o2.z);
      o2.w = fmaf(a2, (float)v5[1], o2.w);
      o3.x = fmaf(a2, (float)v6[0], o3.x);
      o3.y = fmaf(a2, (float)v6[1], o3.y);
      o3.z = fmaf(a2, (float)v7[0], o3.z);
      o3.w = fmaf(a2, (float)v7[1], o3.w);
    }
  }
#undef DOT8

  // ---- combine lane pair; write packed f16 pairs to preLds16 ----
  o0.x += __shfl_xor(o0.x, 1); o0.y += __shfl_xor(o0.y, 1);
  o0.z += __shfl_xor(o0.z, 1); o0.w += __shfl_xor(o0.w, 1);
  o1.x += __shfl_xor(o1.x, 1); o1.y += __shfl_xor(o1.y, 1);
  o1.z += __shfl_xor(o1.z, 1); o1.w += __shfl_xor(o1.w, 1);
  o2.x += __shfl_xor(o2.x, 1); o2.y += __shfl_xor(o2.y, 1);
  o2.z += __shfl_xor(o2.z, 1); o2.w += __shfl_xor(o2.w, 1);
  o3.x += __shfl_xor(o3.x, 1); o3.y += __shfl_xor(o3.y, 1);
  o3.z += __shfl_xor(o3.z, 1); o3.w += __shfl_xor(o3.w, 1);
  {
    unsigned int* pw = preLds16 + pl * PRE16 + (hq >> 1) + split * 4;
    const float4 lo = split ? o2 : o0;
    const float4 hi = split ? o3 : o1;
    pw[0] = h2pack(lo.x, lo.y);
    pw[1] = h2pack(lo.z, lo.w);
    pw[2] = h2pack(hi.x, hi.y);
    pw[3] = h2pack(hi.z, hi.w);
  }
  __syncthreads();

  // ---- fused output projection: 8 groups x 8 cols, w_proj scalar ----------
  const int jb2 = __builtin_amdgcn_readfirstlane(tid >> 6);  // wave-uniform
  const int px2 = tid & 63;
  const int j0 = jb2 * 8;
  const int opix = (th * 8 + (px2 >> 3)) * WP + tw * 8 + (px2 & 7);
  float acc[8];
#pragma unroll
  for (int j = 0; j < 8; ++j) acc[j] = 0.f;
  const unsigned int* prow = preLds16 + px2 * PRE16;
#pragma unroll 8
  for (int cp = 0; cp < 32; ++cp) {
    const h2 hh = ash2(prow[cp]);
    const float xc0 = (float)hh[0];
    const float xc1 = (float)hh[1];
    const float* w0 = w_proj + (2 * cp) * 64 + j0;      // scalar rows
    const float* w1 = w_proj + (2 * cp + 1) * 64 + j0;
#pragma unroll
    for (int j = 0; j < 8; ++j)
      acc[j] = fmaf(xc1, w1[j], fmaf(xc0, w0[j], acc[j]));
  }
#pragma unroll
  for (int j = 0; j < 8; ++j) out[(size_t)(j0 + j) * NPIX + opix] = acc[j];
}

extern "C" void kernel_launch(void* const* d_in, const int* in_sizes, int n_in,
                              void* d_out, int out_size, void* d_ws,
                              size_t ws_size, hipStream_t stream) {
  const float* x = (const float*)d_in[0];
  const float* sims = (const float*)d_in[1];
  const float* w_qk = (const float*)d_in[2];
  const float* w_v = (const float*)d_in[3];
  const float* w_proj = (const float*)d_in[4];
  float* out = (float*)d_out;

  unsigned int* qb16 = (unsigned int*)d_ws;
  unsigned int* kb16 = qb16 + (size_t)NPIX * 32;
  unsigned int* vb16 = kb16 + (size_t)NPIX * 32;

  qkv_kernel<<<dim3(144, 6), 256, 0, stream>>>(x, w_qk, w_v, qb16, kb16, vb16);
  attn_kernel<<<dim3(576), 512, 0, stream>>>(qb16, kb16, vb16, sims, w_proj,
                                             out);
}